// Round 1
// baseline (442.091 us; speedup 1.0000x reference)
//
#include <hip/hip_runtime.h>
#include <hip/hip_bf16.h>
#include <math.h>

// Problem constants (from reference): IN=128, HID=256, EMB=64
// N=10000 nodes, E=640000 edges, P=500000 pairs (read from in_sizes at launch).

// ---------------- degree accumulation ----------------
__global__ void deg_kernel(const int* __restrict__ src, const int* __restrict__ dst,
                           float* __restrict__ degOut, float* __restrict__ degIn, int E) {
    int e = blockIdx.x * blockDim.x + threadIdx.x;
    if (e < E) {
        atomicAdd(&degOut[src[e]], 1.0f);
        atomicAdd(&degIn[dst[e]], 1.0f);
    }
}

// ---------------- block scan over <=10240 bins: rowPtr + fill ----------------
__global__ __launch_bounds__(1024) void scan_kernel(const float* __restrict__ degIn,
                                                    int* __restrict__ rowPtr,
                                                    int* __restrict__ fill,
                                                    int n, int total) {
    __shared__ int part[1024];
    int t = threadIdx.x;
    const int CH = 10;  // 1024*10 >= 10000
    int base = t * CH;
    int run = 0;
    int local[CH];
#pragma unroll
    for (int i = 0; i < CH; ++i) {
        int idx = base + i;
        int c = (idx < n) ? (int)degIn[idx] : 0;
        local[i] = run;
        run += c;
    }
    part[t] = run;
    __syncthreads();
    for (int off = 1; off < 1024; off <<= 1) {
        int v = (t >= off) ? part[t - off] : 0;
        __syncthreads();
        part[t] += v;
        __syncthreads();
    }
    int excl = (t == 0) ? 0 : part[t - 1];
#pragma unroll
    for (int i = 0; i < CH; ++i) {
        int idx = base + i;
        if (idx < n) {
            int val = excl + local[i];
            rowPtr[idx] = val;
            fill[idx] = val;
        }
    }
    if (t == 0) rowPtr[n] = total;
}

// ---------------- deg -> norm (in place) ----------------
__global__ void norm_kernel(float* __restrict__ degOut, float* __restrict__ degIn, int n) {
    int i = blockIdx.x * blockDim.x + threadIdx.x;
    if (i < n) {
        float d0 = degOut[i];
        float d1 = degIn[i];
        degOut[i] = (d0 > 0.f) ? rsqrtf(d0) : 0.f;
        degIn[i]  = (d1 > 0.f) ? rsqrtf(d1) : 0.f;
    }
}

// ---------------- counting-sort scatter: srcSorted grouped by dst ----------------
__global__ void scatter_kernel(const int* __restrict__ src, const int* __restrict__ dst,
                               int* __restrict__ fill, int* __restrict__ srcSorted, int E) {
    int e = blockIdx.x * blockDim.x + threadIdx.x;
    if (e < E) {
        int v = dst[e];
        int pos = atomicAdd(&fill[v], 1);
        srcSorted[pos] = src[e];
    }
}

// ---------------- per-node edge aggregation ----------------
// out[v][c] = normIn[v] * sum_{e in in(v)} normOut[s_e] * h[s_e][c]   (ACT==0)
// ACT==2: out = sigmoid(normIn[v]*sum + bias[c])
template <int D, int ACT>
__global__ void agg_kernel(const float* __restrict__ h,
                           const int* __restrict__ rowPtr,
                           const int* __restrict__ srcSorted,
                           const float* __restrict__ normOut,
                           const float* __restrict__ normIn,
                           const float* __restrict__ bias,
                           float* __restrict__ out) {
    int v = blockIdx.x;
    int c = threadIdx.x;  // D threads
    int beg = rowPtr[v];
    int end = rowPtr[v + 1];
    float acc = 0.f;
    for (int e = beg; e < end; ++e) {
        int s = srcSorted[e];
        float w = normOut[s];
        acc = fmaf(w, h[(size_t)s * D + c], acc);
    }
    float r = acc * normIn[v];
    if (ACT == 2) {
        r = r + bias[c];
        r = 1.f / (1.f + __expf(-r));
    }
    out[(size_t)v * D + c] = r;
}

// ---------------- fp32 tiled GEMM: C[M,N] = A[M,K] @ B[K,N] (+bias, act) ----------------
// BM=BN=64, BK=16, 256 threads, 4x4 per thread. K % 16 == 0, N % 64 == 0.
template <int ACT, bool BIAS>
__global__ __launch_bounds__(256) void gemm_kernel(const float* __restrict__ A,
                                                   const float* __restrict__ B,
                                                   const float* __restrict__ bias,
                                                   float* __restrict__ C,
                                                   int M, int K, int N) {
    __shared__ float As[16][64];  // [k][m] (A transposed in LDS)
    __shared__ float Bs[16][64];  // [k][n]
    int tid = threadIdx.x;
    int bm0 = blockIdx.x * 64;
    int bn0 = blockIdx.y * 64;
    int tx = tid % 16;
    int ty = tid / 16;
    float acc[4][4] = {};
    for (int k0 = 0; k0 < K; k0 += 16) {
        // A tile: 64 rows x 16 k ; each thread one float4
        {
            int r  = tid / 4;
            int kc = (tid % 4) * 4;
            int row = bm0 + r;
            float4 v = make_float4(0.f, 0.f, 0.f, 0.f);
            if (row < M) v = *reinterpret_cast<const float4*>(&A[(size_t)row * K + k0 + kc]);
            As[kc + 0][r] = v.x;
            As[kc + 1][r] = v.y;
            As[kc + 2][r] = v.z;
            As[kc + 3][r] = v.w;
        }
        // B tile: 16 k x 64 n ; each thread one float4
        {
            int kr = tid / 16;
            int nc = (tid % 16) * 4;
            float4 v = *reinterpret_cast<const float4*>(&B[(size_t)(k0 + kr) * N + bn0 + nc]);
            *reinterpret_cast<float4*>(&Bs[kr][nc]) = v;
        }
        __syncthreads();
#pragma unroll
        for (int kk = 0; kk < 16; ++kk) {
            float4 a4 = *reinterpret_cast<const float4*>(&As[kk][ty * 4]);
            float4 b4 = *reinterpret_cast<const float4*>(&Bs[kk][tx * 4]);
            float a[4] = {a4.x, a4.y, a4.z, a4.w};
            float b[4] = {b4.x, b4.y, b4.z, b4.w};
#pragma unroll
            for (int i = 0; i < 4; ++i)
#pragma unroll
                for (int j = 0; j < 4; ++j)
                    acc[i][j] = fmaf(a[i], b[j], acc[i][j]);
        }
        __syncthreads();
    }
#pragma unroll
    for (int i = 0; i < 4; ++i) {
        int row = bm0 + ty * 4 + i;
        if (row >= M) continue;
#pragma unroll
        for (int j = 0; j < 4; ++j) {
            int col = bn0 + tx * 4 + j;
            float v = acc[i][j];
            if (BIAS) v += bias[col];
            if (ACT == 1) v = fmaxf(v, 0.f);
            C[(size_t)row * N + col] = v;
        }
    }
}

// ---------------- per-node output dots: a[v], b[v] ----------------
__global__ void ab_kernel(const float* __restrict__ g, const float* __restrict__ Wout,
                          float* __restrict__ av, float* __restrict__ bv) {
    int v = blockIdx.x;
    int c = threadIdx.x;  // 64
    float p = g[(size_t)v * 64 + c];
    float pa = p * Wout[c];
    float pb = p * Wout[64 + c];
#pragma unroll
    for (int off = 32; off > 0; off >>= 1) {
        pa += __shfl_down(pa, off);
        pb += __shfl_down(pb, off);
    }
    if (c == 0) {
        av[v] = pa;
        bv[v] = pb;
    }
}

// ---------------- final: out[p] = tanh(a[o] + b[d] + dis[o,d]*w128 + bout) ----------------
__global__ void final_kernel(const int* __restrict__ ti, const float* __restrict__ av,
                             const float* __restrict__ bv, const float* __restrict__ dis,
                             const float* __restrict__ Wout, const float* __restrict__ bout,
                             float* __restrict__ out, int P, int N) {
    int p = blockIdx.x * blockDim.x + threadIdx.x;
    if (p >= P) return;
    int o = ti[p];
    int d = ti[P + p];
    float w128 = Wout[128];
    float b0 = bout[0];
    float s = av[o] + bv[d] + dis[(size_t)o * N + d] * w128 + b0;
    out[p] = tanhf(s);
}

extern "C" void kernel_launch(void* const* d_in, const int* in_sizes, int n_in,
                              void* d_out, int out_size, void* d_ws, size_t ws_size,
                              hipStream_t stream) {
    const float* x    = (const float*)d_in[0];
    const float* dis  = (const float*)d_in[1];
    const float* W1   = (const float*)d_in[2];
    const float* b1   = (const float*)d_in[3];
    const float* W2   = (const float*)d_in[4];
    const float* b2   = (const float*)d_in[5];
    const float* W3   = (const float*)d_in[6];
    const float* b3   = (const float*)d_in[7];
    const float* Wout = (const float*)d_in[8];
    const float* bout = (const float*)d_in[9];
    const int*   src  = (const int*)d_in[10];
    const int*   dst  = (const int*)d_in[11];
    const int*   ti   = (const int*)d_in[12];
    float* out = (float*)d_out;

    const int IN = 128, HID = 256, EMB = 64;
    const int N = in_sizes[0] / IN;       // 10000
    const int E = in_sizes[10];           // 640000
    const int P = in_sizes[12] / 2;       // 500000

    // workspace layout (256B aligned chunks)
    char* ws = (char*)d_ws;
    size_t off = 0;
    auto alloc = [&](size_t bytes) {
        size_t o = off;
        off = (off + bytes + 255) & ~(size_t)255;
        return o;
    };
    size_t o_norms    = alloc((size_t)2 * N * sizeof(float));  // degOut|degIn -> normOut|normIn
    size_t o_rowPtr   = alloc((size_t)(N + 1) * sizeof(int));
    size_t o_fill     = alloc((size_t)N * sizeof(int));
    size_t o_srcSort  = alloc((size_t)E * sizeof(int));
    size_t o_bufA     = alloc((size_t)N * 256 * sizeof(float));
    size_t o_bufB     = alloc((size_t)N * 256 * sizeof(float));
    size_t o_av       = alloc((size_t)N * sizeof(float));
    size_t o_bv       = alloc((size_t)N * sizeof(float));
    (void)ws_size;

    float* normOut  = (float*)(ws + o_norms);
    float* normIn   = normOut + N;
    int*   rowPtr   = (int*)(ws + o_rowPtr);
    int*   fill     = (int*)(ws + o_fill);
    int*   srcSort  = (int*)(ws + o_srcSort);
    float* bufA     = (float*)(ws + o_bufA);
    float* bufB     = (float*)(ws + o_bufB);
    float* av       = (float*)(ws + o_av);
    float* bv       = (float*)(ws + o_bv);

    // 1. zero degree accumulators
    hipMemsetAsync(normOut, 0, (size_t)2 * N * sizeof(float), stream);

    // 2. degrees
    deg_kernel<<<(E + 255) / 256, 256, 0, stream>>>(src, dst, normOut, normIn, E);

    // 3. rowPtr + fill from deg_in
    scan_kernel<<<1, 1024, 0, stream>>>(normIn, rowPtr, fill, N, E);

    // 4. norms in place
    norm_kernel<<<(N + 255) / 256, 256, 0, stream>>>(normOut, normIn, N);

    // 5. sort edges by dst
    scatter_kernel<<<(E + 255) / 256, 256, 0, stream>>>(src, dst, fill, srcSort, E);

    // 6. layer1: agg(x) [N,128] -> bufA ; gemm -> relu -> bufB [N,256]
    agg_kernel<128, 0><<<N, 128, 0, stream>>>(x, rowPtr, srcSort, normOut, normIn, nullptr, bufA);
    {
        dim3 grid((N + 63) / 64, HID / 64);
        gemm_kernel<1, true><<<grid, 256, 0, stream>>>(bufA, W1, b1, bufB, N, IN, HID);
    }

    // 7. layer2: agg(bufB) [N,256] -> bufA ; gemm -> relu -> bufB [N,256]
    agg_kernel<256, 0><<<N, 256, 0, stream>>>(bufB, rowPtr, srcSort, normOut, normIn, nullptr, bufA);
    {
        dim3 grid((N + 63) / 64, HID / 64);
        gemm_kernel<1, true><<<grid, 256, 0, stream>>>(bufA, W2, b2, bufB, N, HID, HID);
    }

    // 8. layer3 (reordered): gemm bufB@W3 -> bufA [N,64]; agg+sigmoid -> bufB [N,64]
    {
        dim3 grid((N + 63) / 64, EMB / 64);
        gemm_kernel<0, false><<<grid, 256, 0, stream>>>(bufB, W3, nullptr, bufA, N, HID, EMB);
    }
    agg_kernel<64, 2><<<N, 64, 0, stream>>>(bufA, rowPtr, srcSort, normOut, normIn, b3, bufB);

    // 9. per-node output dots
    ab_kernel<<<N, 64, 0, stream>>>(bufB, Wout, av, bv);

    // 10. final gather + tanh
    final_kernel<<<(P + 255) / 256, 256, 0, stream>>>(ti, av, bv, dis, Wout, bout, out, P, N);
}

// Round 2
// 282.322 us; speedup vs baseline: 1.5659x; 1.5659x over previous
//
#include <hip/hip_runtime.h>
#include <hip/hip_bf16.h>
#include <math.h>

typedef __attribute__((ext_vector_type(8))) short short8;
typedef __attribute__((ext_vector_type(4))) float f32x4;

// ---------- bf16 helpers (RNE) ----------
__device__ __forceinline__ ushort f2bf(float f) {
    uint u = __float_as_uint(f);
    return (ushort)((u + 0x7FFFu + ((u >> 16) & 1u)) >> 16);
}
__device__ __forceinline__ float bfl(uint r) { return __uint_as_float(r << 16); }
__device__ __forceinline__ float bfh(uint r) { return __uint_as_float(r & 0xFFFF0000u); }

// ---------------- degree accumulation ----------------
__global__ void deg_kernel(const int* __restrict__ src, const int* __restrict__ dst,
                           float* __restrict__ degOut, float* __restrict__ degIn, int E) {
    int e = blockIdx.x * blockDim.x + threadIdx.x;
    if (e < E) {
        atomicAdd(&degOut[src[e]], 1.0f);
        atomicAdd(&degIn[dst[e]], 1.0f);
    }
}

// ---------------- block scan over <=10240 bins ----------------
__global__ __launch_bounds__(1024) void scan_kernel(const float* __restrict__ degIn,
                                                    int* __restrict__ rowPtr,
                                                    int* __restrict__ fill,
                                                    int n, int total) {
    __shared__ int part[1024];
    int t = threadIdx.x;
    const int CH = 10;
    int base = t * CH;
    int run = 0;
    int local[CH];
#pragma unroll
    for (int i = 0; i < CH; ++i) {
        int idx = base + i;
        int c = (idx < n) ? (int)degIn[idx] : 0;
        local[i] = run;
        run += c;
    }
    part[t] = run;
    __syncthreads();
    for (int off = 1; off < 1024; off <<= 1) {
        int v = (t >= off) ? part[t - off] : 0;
        __syncthreads();
        part[t] += v;
        __syncthreads();
    }
    int excl = (t == 0) ? 0 : part[t - 1];
#pragma unroll
    for (int i = 0; i < CH; ++i) {
        int idx = base + i;
        if (idx < n) {
            int val = excl + local[i];
            rowPtr[idx] = val;
            fill[idx] = val;
        }
    }
    if (t == 0) rowPtr[n] = total;
}

// ---------------- deg -> norm (in place) ----------------
__global__ void norm_kernel(float* __restrict__ degOut, float* __restrict__ degIn, int n) {
    int i = blockIdx.x * blockDim.x + threadIdx.x;
    if (i < n) {
        float d0 = degOut[i];
        float d1 = degIn[i];
        degOut[i] = (d0 > 0.f) ? rsqrtf(d0) : 0.f;
        degIn[i]  = (d1 > 0.f) ? rsqrtf(d1) : 0.f;
    }
}

// ---------------- counting-sort: (src, normOut[src]) grouped by dst ----------------
__global__ void scatter_kernel(const int* __restrict__ src, const int* __restrict__ dst,
                               const float* __restrict__ normOut,
                               int* __restrict__ fill, int2* __restrict__ edge, int E) {
    int e = blockIdx.x * blockDim.x + threadIdx.x;
    if (e < E) {
        int s = src[e];
        int v = dst[e];
        int pos = atomicAdd(&fill[v], 1);
        edge[pos] = make_int2(s, __float_as_int(normOut[s]));
    }
}

// ---------------- fused fp32 -> bf16 conversions ----------------
__global__ void cvt_all_kernel(const float* __restrict__ x,  ushort* __restrict__ xo,  int nx,
                               const float* __restrict__ w1, ushort* __restrict__ w1o, int n1,
                               const float* __restrict__ w2, ushort* __restrict__ w2o, int n2,
                               const float* __restrict__ w3, ushort* __restrict__ w3o, int n3) {
    int i = blockIdx.x * blockDim.x + threadIdx.x;
    if (i < nx) { xo[i] = f2bf(x[i]); return; }
    i -= nx;
    if (i < n1) { w1o[i] = f2bf(w1[i]); return; }
    i -= n1;
    if (i < n2) { w2o[i] = f2bf(w2[i]); return; }
    i -= n2;
    if (i < n3) w3o[i] = f2bf(w3[i]);
}

// ---------------- per-node bf16 edge aggregation (4 nodes / 256-thr block) ----------------
template <int D, int ACT>
__global__ __launch_bounds__(256) void agg_bf16_k(const ushort* __restrict__ h,
                                                  const int* __restrict__ rowPtr,
                                                  const int2* __restrict__ edge,
                                                  const float* __restrict__ normIn,
                                                  const float* __restrict__ bias,
                                                  const float* __restrict__ Wout,
                                                  ushort* __restrict__ out,
                                                  float* __restrict__ av, float* __restrict__ bv,
                                                  int N) {
    constexpr int V = D / 64;
    int v = blockIdx.x * 4 + (threadIdx.x >> 6);
    if (v >= N) return;
    int l = threadIdx.x & 63;

    int beg = rowPtr[v];
    int end = rowPtr[v + 1];
    float acc[V] = {};
    const ushort* hb = h + (size_t)l * V;

    auto body = [&](int2 ed) {
        float w = __int_as_float(ed.y);
        const ushort* p = hb + (size_t)ed.x * D;
        if constexpr (V == 1) {
            acc[0] = fmaf(w, bfl((uint)p[0]), acc[0]);
        } else if constexpr (V == 2) {
            uint r = *(const uint*)p;
            acc[0] = fmaf(w, bfl(r), acc[0]);
            acc[1] = fmaf(w, bfh(r), acc[1]);
        } else {
            uint2 r = *(const uint2*)p;
            acc[0] = fmaf(w, bfl(r.x), acc[0]);
            acc[1] = fmaf(w, bfh(r.x), acc[1]);
            acc[2] = fmaf(w, bfl(r.y), acc[2]);
            acc[3] = fmaf(w, bfh(r.y), acc[3]);
        }
    };

    int e = beg;
    for (; e + 4 <= end; e += 4) {
        int2 e0 = edge[e + 0];
        int2 e1 = edge[e + 1];
        int2 e2 = edge[e + 2];
        int2 e3 = edge[e + 3];
        body(e0); body(e1); body(e2); body(e3);
    }
    for (; e < end; ++e) body(edge[e]);

    float nin = normIn[v];
    if (ACT == 0) {
        ushort o[V];
#pragma unroll
        for (int j = 0; j < V; ++j) o[j] = f2bf(acc[j] * nin);
        if constexpr (V == 1) {
            out[(size_t)v * D + l] = o[0];
        } else if constexpr (V == 2) {
            *(uint*)&out[(size_t)v * D + l * 2] = (uint)o[0] | ((uint)o[1] << 16);
        } else {
            uint2 pk;
            pk.x = (uint)o[0] | ((uint)o[1] << 16);
            pk.y = (uint)o[2] | ((uint)o[3] << 16);
            *(uint2*)&out[(size_t)v * D + l * 4] = pk;
        }
    } else {
        float g = acc[0] * nin + bias[l];
        g = 1.f / (1.f + __expf(-g));
        float pa = g * Wout[l];
        float pb = g * Wout[64 + l];
#pragma unroll
        for (int off = 32; off > 0; off >>= 1) {
            pa += __shfl_down(pa, off);
            pb += __shfl_down(pb, off);
        }
        if (l == 0) {
            av[v] = pa;
            bv[v] = pb;
        }
    }
}

// ---------------- bf16 MFMA GEMM ----------------
template <int BM, int ACT, bool BIAS>
__global__ __launch_bounds__(256) void gemm_bf16(const ushort* __restrict__ A,
                                                 const ushort* __restrict__ B,
                                                 const float* __restrict__ bias,
                                                 ushort* __restrict__ C,
                                                 int M, int K, int N) {
    constexpr int WR = BM / 64;
    __shared__ ushort As[BM * 40];
    __shared__ ushort Bs[64 * 40];

    int tid  = threadIdx.x;
    int wave = tid >> 6;
    int lane = tid & 63;
    int l15  = lane & 15;
    int l4   = lane >> 4;
    int m0 = blockIdx.x * BM;
    int n0 = blockIdx.y * 64;

    f32x4 acc[WR][4] = {};

    for (int k0 = 0; k0 < K; k0 += 32) {
#pragma unroll
        for (int p = 0; p < BM / 64; ++p) {
            int idx = p * 256 + tid;
            int row = idx >> 2;
            int c8  = (idx & 3) * 8;
            short8 val = {};
            int grow = m0 + row;
            if (grow < M) val = *(const short8*)&A[(size_t)grow * K + k0 + c8];
            *(short8*)&As[row * 40 + c8] = val;
        }
        {
            int k  = tid & 31;
            int n8 = (tid >> 5) * 8;
            short8 val = *(const short8*)&B[(size_t)(k0 + k) * N + n0 + n8];
#pragma unroll
            for (int j = 0; j < 8; ++j) Bs[(n8 + j) * 40 + k] = (ushort)val[j];
        }
        __syncthreads();

        short8 bf[4];
#pragma unroll
        for (int n = 0; n < 4; ++n)
            bf[n] = *(const short8*)&Bs[(n * 16 + l15) * 40 + l4 * 8];
#pragma unroll
        for (int r = 0; r < WR; ++r) {
            int row = wave * (16 * WR) + r * 16 + l15;
            short8 af = *(const short8*)&As[row * 40 + l4 * 8];
#pragma unroll
            for (int n = 0; n < 4; ++n)
                acc[r][n] = __builtin_amdgcn_mfma_f32_16x16x32_bf16(af, bf[n], acc[r][n], 0, 0, 0);
        }
        __syncthreads();
    }

#pragma unroll
    for (int r = 0; r < WR; ++r) {
        int rowb = m0 + wave * (16 * WR) + r * 16 + l4 * 4;
#pragma unroll
        for (int n = 0; n < 4; ++n) {
            int col = n0 + n * 16 + l15;
            float bsv = BIAS ? bias[col] : 0.f;
#pragma unroll
            for (int q = 0; q < 4; ++q) {
                int row = rowb + q;
                if (row < M) {
                    float vv = acc[r][n][q] + bsv;
                    if (ACT == 1) vv = fmaxf(vv, 0.f);
                    C[(size_t)row * N + col] = f2bf(vv);
                }
            }
        }
    }
}

// ---------------- final gather + tanh ----------------
__global__ void final_kernel(const int* __restrict__ ti, const float* __restrict__ av,
                             const float* __restrict__ bv, const float* __restrict__ dis,
                             const float* __restrict__ Wout, const float* __restrict__ bout,
                             float* __restrict__ out, int P, int N) {
    int p = blockIdx.x * blockDim.x + threadIdx.x;
    if (p >= P) return;
    int o = ti[p];
    int d = ti[P + p];
    float s = av[o] + bv[d] + dis[(size_t)o * N + d] * Wout[128] + bout[0];
    out[p] = tanhf(s);
}

extern "C" void kernel_launch(void* const* d_in, const int* in_sizes, int n_in,
                              void* d_out, int out_size, void* d_ws, size_t ws_size,
                              hipStream_t stream) {
    const float* x    = (const float*)d_in[0];
    const float* dis  = (const float*)d_in[1];
    const float* W1   = (const float*)d_in[2];
    const float* b1   = (const float*)d_in[3];
    const float* W2   = (const float*)d_in[4];
    const float* b2   = (const float*)d_in[5];
    const float* W3   = (const float*)d_in[6];
    const float* b3   = (const float*)d_in[7];
    const float* Wout = (const float*)d_in[8];
    const float* bout = (const float*)d_in[9];
    const int*   src  = (const int*)d_in[10];
    const int*   dst  = (const int*)d_in[11];
    const int*   ti   = (const int*)d_in[12];
    float* out = (float*)d_out;

    const int IN = 128, HID = 256, EMB = 64;
    const int N = in_sizes[0] / IN;
    const int E = in_sizes[10];
    const int P = in_sizes[12] / 2;

    char* ws = (char*)d_ws;
    size_t off = 0;
    auto alloc = [&](size_t bytes) {
        size_t o = off;
        off = (off + bytes + 255) & ~(size_t)255;
        return o;
    };
    size_t o_norms  = alloc((size_t)2 * N * sizeof(float));
    size_t o_rowPtr = alloc((size_t)(N + 1) * sizeof(int));
    size_t o_fill   = alloc((size_t)N * sizeof(int));
    size_t o_edge   = alloc((size_t)E * sizeof(int2));
    size_t o_xbf    = alloc((size_t)N * IN * sizeof(ushort));
    size_t o_wbf    = alloc((size_t)(IN * HID + HID * HID + HID * EMB) * sizeof(ushort));
    size_t o_bufA   = alloc((size_t)N * HID * sizeof(ushort));
    size_t o_bufB   = alloc((size_t)N * HID * sizeof(ushort));
    size_t o_av     = alloc((size_t)N * sizeof(float));
    size_t o_bv     = alloc((size_t)N * sizeof(float));
    (void)ws_size;

    float*  normOut = (float*)(ws + o_norms);
    float*  normIn  = normOut + N;
    int*    rowPtr  = (int*)(ws + o_rowPtr);
    int*    fill    = (int*)(ws + o_fill);
    int2*   edge    = (int2*)(ws + o_edge);
    ushort* xbf     = (ushort*)(ws + o_xbf);
    ushort* w1bf    = (ushort*)(ws + o_wbf);
    ushort* w2bf    = w1bf + IN * HID;
    ushort* w3bf    = w2bf + HID * HID;
    ushort* bufA    = (ushort*)(ws + o_bufA);
    ushort* bufB    = (ushort*)(ws + o_bufB);
    float*  av      = (float*)(ws + o_av);
    float*  bv      = (float*)(ws + o_bv);

    hipMemsetAsync(normOut, 0, (size_t)2 * N * sizeof(float), stream);
    deg_kernel<<<(E + 255) / 256, 256, 0, stream>>>(src, dst, normOut, normIn, E);
    scan_kernel<<<1, 1024, 0, stream>>>(normIn, rowPtr, fill, N, E);
    norm_kernel<<<(N + 255) / 256, 256, 0, stream>>>(normOut, normIn, N);
    scatter_kernel<<<(E + 255) / 256, 256, 0, stream>>>(src, dst, normOut, fill, edge, E);
    {
        int nx = N * IN, n1 = IN * HID, n2 = HID * HID, n3 = HID * EMB;
        int tot = nx + n1 + n2 + n3;
        cvt_all_kernel<<<(tot + 255) / 256, 256, 0, stream>>>(x, xbf, nx, W1, w1bf, n1,
                                                              W2, w2bf, n2, W3, w3bf, n3);
    }

    int aggGrid = (N + 3) / 4;

    agg_bf16_k<128, 0><<<aggGrid, 256, 0, stream>>>(xbf, rowPtr, edge, normIn, nullptr, nullptr,
                                                    bufA, nullptr, nullptr, N);
    {
        dim3 grid((N + 127) / 128, HID / 64);
        gemm_bf16<128, 1, true><<<grid, 256, 0, stream>>>(bufA, w1bf, b1, bufB, N, IN, HID);
    }
    agg_bf16_k<256, 0><<<aggGrid, 256, 0, stream>>>(bufB, rowPtr, edge, normIn, nullptr, nullptr,
                                                    bufA, nullptr, nullptr, N);
    {
        dim3 grid((N + 127) / 128, HID / 64);
        gemm_bf16<128, 1, true><<<grid, 256, 0, stream>>>(bufA, w2bf, b2, bufB, N, HID, HID);
    }
    {
        dim3 grid((N + 63) / 64, EMB / 64);
        gemm_bf16<64, 0, false><<<grid, 256, 0, stream>>>(bufB, w3bf, nullptr, bufA, N, HID, EMB);
    }
    agg_bf16_k<64, 2><<<aggGrid, 256, 0, stream>>>(bufA, rowPtr, edge, normIn, b3, Wout,
                                                   nullptr, av, bv, N);
    final_kernel<<<(P + 255) / 256, 256, 0, stream>>>(ti, av, bv, dis, Wout, bout, out, P, N);
}